// Round 2
// baseline (1066.570 us; speedup 1.0000x reference)
//
#include <hip/hip_runtime.h>
#include <math.h>

#define B_ 512
#define T_ 200
#define D_ 256
#define H_ 256

typedef unsigned int   u32;
typedef unsigned short u16;
typedef _Float16 half8 __attribute__((ext_vector_type(8)));
typedef float f32x4 __attribute__((ext_vector_type(4)));

__device__ __forceinline__ float sigmoid_f(float x) { return 1.0f / (1.0f + __expf(-x)); }
__device__ __forceinline__ float tanh_f(float x)    { return 1.0f - 2.0f / (__expf(2.0f * x) + 1.0f); }
__device__ __forceinline__ u16 f16b(float x) { union { _Float16 h; u16 u; } r; r.h = (_Float16)x; return r.u; }
__device__ __forceinline__ float f16f(u16 v) { union { u16 u; _Float16 h; } r; r.u = v; return (float)r.h; }

// Fragment-major f16 weight copies. Layout: [tile][kstep][lane][8] where the
// 8 halves at lane l are W[k = kstep*32 + (l>>4)*8 + 0..7][col = tile*16 + (l&15)].
// This is simultaneously a valid MFMA A-frag (i=l&15) and B-frag (j=l&15).
// g_Wt: x-part rows 0..255 (tiles 0..31 gate, 32..47 cand).
// g_Wh: h-part rows 256..511 (same tiling).
__device__ __attribute__((aligned(16))) _Float16 g_Wt[48 * 8 * 64 * 8];
__device__ __attribute__((aligned(16))) _Float16 g_Wh[48 * 8 * 64 * 8];

__global__ __launch_bounds__(512) void prep_wt(
    const float* __restrict__ gk, const float* __restrict__ ck)
{
    const int  blk  = blockIdx.x;        // 0..95
    const bool isH  = blk >= 48;
    const int  ct   = isH ? blk - 48 : blk;
    const int  step = threadIdx.x >> 6;  // 0..7
    const int  lane = threadIdx.x & 63;
    const bool isG  = ct < 32;
    const float* W  = isG ? gk : ck;
    const int  nc   = isG ? 512 : 256;
    const int  col  = (isG ? ct : ct - 32) * 16 + (lane & 15);
    const int  k0   = step * 32 + (lane >> 4) * 8 + (isH ? 256 : 0);
    half8 v;
    #pragma unroll
    for (int j = 0; j < 8; ++j)
        v[j] = (_Float16)W[(size_t)(k0 + j) * nc + col];
    _Float16* dst = isH ? g_Wh : g_Wt;
    *(half8*)&dst[((size_t)(ct * 8 + step) * 64 + lane) * 8] = v;
}

// ============================================================================
// Projection GEMM: proj = x @ W_x (+bias). A = x (i = batch row), B = W
// (j = output col). D: row i = (lane>>4)*4+reg, col j = lane&15 (HW-verified).
// Epilogue: scalar u16 stores, 16 consecutive cols per 16-lane group
// (4 x 32B segments per store instr vs previous 64 x 8B scatter).
// pg layout is now plain u16 [m][512], index = gate col.
// ============================================================================
__global__ __launch_bounds__(512, 2) void proj_mfma(
    const float* __restrict__ x, const float* __restrict__ gb,
    const float* __restrict__ cb,
    u16* pg,                      // aliases d_out: [102400][512] u16
    u16* __restrict__ pc)         // ws: [102400][256] u16
{
    __shared__ _Float16 xs[64][264];   // +8 f16 pad: conflict-free b128 reads
    const int tid  = threadIdx.x;
    const int m0   = blockIdx.x * 64;
    const int lane = tid & 63;
    const int w    = tid >> 6;

    // ---- stage x tile fp32 -> f16 LDS (coalesced float4 loads) ----
    #pragma unroll
    for (int q = 0; q < 8; ++q) {
        int f = tid + 512 * q;
        int r = f >> 6, c = (f & 63) * 4;
        float4 v = *(const float4*)&x[(size_t)(m0 + r) * 256 + c];
        uint2 p;
        union { _Float16 h[2]; u32 u; } t0, t1;
        t0.h[0] = (_Float16)v.x; t0.h[1] = (_Float16)v.y;
        t1.h[0] = (_Float16)v.z; t1.h[1] = (_Float16)v.w;
        p.x = t0.u; p.y = t1.u;
        *(uint2*)&xs[r][c] = p;
    }
    __syncthreads();

    // ---- A-fragments (x) for the whole block: 128 VGPRs, read once ----
    half8 xf[4][8];
    #pragma unroll
    for (int jt = 0; jt < 4; ++jt)
        #pragma unroll
        for (int kc = 0; kc < 8; ++kc)
            xf[jt][kc] = *(const half8*)&xs[jt * 16 + (lane & 15)]
                                           [kc * 32 + (lane >> 4) * 8];

    const int qr4 = (lane >> 4) * 4;

    #pragma unroll 1
    for (int p = 0; p < 6; ++p) {
        const int it = w + 8 * p;       // col tile 0..47 (wave-uniform)
        const _Float16* bp = &g_Wt[(size_t)it * 4096];
        half8 bf[8];
        #pragma unroll
        for (int kc = 0; kc < 8; ++kc)
            bf[kc] = *(const half8*)&bp[(kc * 64 + lane) * 8];

        f32x4 acc[4] = {};
        #pragma unroll
        for (int kc = 0; kc < 8; ++kc)
            #pragma unroll
            for (int jt = 0; jt < 4; ++jt)
                acc[jt] = __builtin_amdgcn_mfma_f32_16x16x32_f16(
                              xf[jt][kc], bf[kc], acc[jt], 0, 0, 0);

        const int n = it * 16 + (lane & 15);    // output col 0..767
        const float bias = (it < 32) ? gb[n] : cb[n - 512];
        if (it < 32) {
            #pragma unroll
            for (int jt = 0; jt < 4; ++jt)
                #pragma unroll
                for (int r = 0; r < 4; ++r) {
                    int m = m0 + jt * 16 + qr4 + r;
                    pg[(size_t)m * 512 + n] = f16b(acc[jt][r] + bias);
                }
        } else {
            #pragma unroll
            for (int jt = 0; jt < 4; ++jt)
                #pragma unroll
                for (int r = 0; r < 4; ++r) {
                    int m = m0 + jt * 16 + qr4 + r;
                    pc[(size_t)m * 256 + (n - 512)] = f16b(acc[jt][r] + bias);
                }
        }
    }
}

// ============================================================================
// Recurrent kernel v3: MFMA recurrence. 32 blocks x 512 thr, 16 batch rows.
// A = h (16x256 f16, padded LDS), B = weight fragments in registers (192/thr).
// Wave w: reset tiles {2w,2w+1} (cols 32w..+31), update {16+2w,17+2w},
// cand {32+2w,33+2w}. D: row=(lane>>4)*4+reg (batch), col=tile*16+(lane&15).
// Each lane statically owns 8 (row,col) cells -> h_old cached in registers.
// 48 MFMA/wave/step, 16 b128 + 16 b16 LDS ops/wave/step, 2 barriers/step.
// ============================================================================
__global__ __launch_bounds__(512) void gru_rec3(
    const int* __restrict__ slen,
    const u16* pg,                 // aliases d_out: [m][512] u16
    const u16* __restrict__ pc,    // ws: [m][256] u16
    float* out)                    // aliases pg (barrier-ordered read-then-write)
{
    __shared__ _Float16 h_lds[16][264];   // pad 8 halves: bank-balanced b128
    __shared__ _Float16 rh_lds[16][264];

    const int tid  = threadIdx.x;
    const int w    = tid >> 6;       // wave 0..7
    const int lane = tid & 63;
    const int qr   = lane >> 4;      // 0..3
    const int cl   = lane & 15;
    const int b0   = blockIdx.x * 16;
    const int colR0 = 32 * w + cl;   // reset/cand col of tile tt=0

    // ---- one-time: weight fragments into registers (AGPR-friendly) ----
    half8 wr[2][8], wu[2][8], wc8[2][8];
    #pragma unroll
    for (int tt = 0; tt < 2; ++tt)
        #pragma unroll
        for (int s = 0; s < 8; ++s) {
            wr[tt][s]  = *(const half8*)&g_Wh[(((size_t)(2 * w + tt) * 8 + s) * 64 + lane) * 8];
            wu[tt][s]  = *(const half8*)&g_Wh[(((size_t)(16 + 2 * w + tt) * 8 + s) * 64 + lane) * 8];
            wc8[tt][s] = *(const half8*)&g_Wh[(((size_t)(32 + 2 * w + tt) * 8 + s) * 64 + lane) * 8];
        }

    // ---- init h = 0 ----
    for (int i = tid; i < 16 * 264; i += 512)
        ((_Float16*)h_lds)[i] = (_Float16)0.0f;

    // per-lane static cells: rows qr*4+r, cols colR0 + tt*16
    int lenr[4];
    #pragma unroll
    for (int r = 0; r < 4; ++r) lenr[r] = slen[b0 + qr * 4 + r];

    const u16* pgp[4]; const u16* pcp[4]; float* outp[4];
    #pragma unroll
    for (int r = 0; r < 4; ++r) {
        size_t m = (size_t)(b0 + qr * 4 + r) * T_;
        pgp[r]  = pg  + m * 512 + colR0;
        pcp[r]  = pc  + m * 256 + colR0;
        outp[r] = out + m * 256 + colR0;
    }

    float hold[2][4] = {};
    float uu[2][4];

    for (int t = 0; t < T_; ++t) {
        // ---- prefetch this step's projections (consumed after barrier) ----
        float prr[2][4], pru[2][4], prc[2][4];
        #pragma unroll
        for (int tt = 0; tt < 2; ++tt)
            #pragma unroll
            for (int r = 0; r < 4; ++r) {
                prr[tt][r] = f16f(__builtin_nontemporal_load(pgp[r] + tt * 16));
                pru[tt][r] = f16f(__builtin_nontemporal_load(pgp[r] + 256 + tt * 16));
                prc[tt][r] = f16f(__builtin_nontemporal_load(pcp[r] + tt * 16));
            }

        __syncthreads();                  // A: h(t-1) writes visible

        // ---- gates: h @ Wg ----
        half8 ha[8];
        #pragma unroll
        for (int s = 0; s < 8; ++s)
            ha[s] = *(const half8*)&h_lds[cl][s * 32 + qr * 8];

        f32x4 ar[2] = {}, au[2] = {};
        #pragma unroll
        for (int s = 0; s < 8; ++s)
            #pragma unroll
            for (int tt = 0; tt < 2; ++tt) {
                ar[tt] = __builtin_amdgcn_mfma_f32_16x16x32_f16(ha[s], wr[tt][s],  ar[tt], 0, 0, 0);
                au[tt] = __builtin_amdgcn_mfma_f32_16x16x32_f16(ha[s], wu[tt][s],  au[tt], 0, 0, 0);
            }

        #pragma unroll
        for (int tt = 0; tt < 2; ++tt)
            #pragma unroll
            for (int r = 0; r < 4; ++r) {
                float rv = sigmoid_f(ar[tt][r] + prr[tt][r]);
                uu[tt][r] = sigmoid_f(au[tt][r] + pru[tt][r]);
                rh_lds[qr * 4 + r][colR0 + tt * 16] = (_Float16)(rv * hold[tt][r]);
            }

        __syncthreads();                  // B: rh ready

        // ---- candidate: (r*h) @ Wc ----
        half8 ra[8];
        #pragma unroll
        for (int s = 0; s < 8; ++s)
            ra[s] = *(const half8*)&rh_lds[cl][s * 32 + qr * 8];

        f32x4 ac0[2] = {}, ac1[2] = {};   // 4 chains for MFMA latency
        #pragma unroll
        for (int s = 0; s < 8; s += 2)
            #pragma unroll
            for (int tt = 0; tt < 2; ++tt) {
                ac0[tt] = __builtin_amdgcn_mfma_f32_16x16x32_f16(ra[s],     wc8[tt][s],     ac0[tt], 0, 0, 0);
                ac1[tt] = __builtin_amdgcn_mfma_f32_16x16x32_f16(ra[s + 1], wc8[tt][s + 1], ac1[tt], 0, 0, 0);
            }

        #pragma unroll
        for (int tt = 0; tt < 2; ++tt)
            #pragma unroll
            for (int r = 0; r < 4; ++r) {
                float cd = tanh_f(ac0[tt][r] + ac1[tt][r] + prc[tt][r]);
                float u  = uu[tt][r];
                float hn = u * hold[tt][r] + (1.0f - u) * cd;
                bool  valid = (t < lenr[r]);
                __builtin_nontemporal_store(valid ? hn : 0.0f, outp[r] + tt * 16);
                if (valid) {
                    hold[tt][r] = hn;
                    h_lds[qr * 4 + r][colR0 + tt * 16] = (_Float16)hn;
                }
            }

        #pragma unroll
        for (int r = 0; r < 4; ++r) { pgp[r] += 512; pcp[r] += 256; outp[r] += 256; }
    }
}

extern "C" void kernel_launch(void* const* d_in, const int* in_sizes, int n_in,
                              void* d_out, int out_size, void* d_ws, size_t ws_size,
                              hipStream_t stream) {
    const float* x    = (const float*)d_in[0];
    const int*   slen = (const int*)  d_in[1];
    const float* gk   = (const float*)d_in[2];
    const float* gb   = (const float*)d_in[3];
    const float* ck   = (const float*)d_in[4];
    const float* cb   = (const float*)d_in[5];
    float* out = (float*)d_out;
    u16*   pg  = (u16*)d_out;   // [102400][512] u16 == 104.86 MB == out size
    u16*   pc  = (u16*)d_ws;    // 52.4 MB cand x-proj

    prep_wt<<<dim3(96), 512, 0, stream>>>(gk, ck);
    proj_mfma<<<dim3(1600), 512, 0, stream>>>(x, gb, cb, pg, pc);
    gru_rec3<<<dim3(32), 512, 0, stream>>>(slen, pg, pc, out);
}

// Round 3
// 994.937 us; speedup vs baseline: 1.0720x; 1.0720x over previous
//
#include <hip/hip_runtime.h>
#include <math.h>

#define B_ 512
#define T_ 200
#define D_ 256
#define H_ 256

typedef unsigned int   u32;
typedef unsigned short u16;
typedef _Float16 half8 __attribute__((ext_vector_type(8)));
typedef float f32x4 __attribute__((ext_vector_type(4)));

__device__ __forceinline__ float sigmoid_f(float x) { return 1.0f / (1.0f + __expf(-x)); }
__device__ __forceinline__ float tanh_f(float x)    { return 1.0f - 2.0f / (__expf(2.0f * x) + 1.0f); }
__device__ __forceinline__ u16 f16b(float x) { union { _Float16 h; u16 u; } r; r.h = (_Float16)x; return r.u; }
__device__ __forceinline__ float f16f(u16 v) { union { u16 u; _Float16 h; } r; r.u = v; return (float)r.h; }

// Raw barrier: drain LDS ops only; global loads/stores stay in flight
// (avoids the compiler's vmcnt(0) drain before s_barrier).
#define BARX() asm volatile("s_waitcnt lgkmcnt(0)\n\ts_barrier" ::: "memory")

// Fragment-major f16 weight copies. [tile][kstep][lane][8]: lane l holds
// W[k = kstep*32 + (l>>4)*8 + 0..7][col = tile*16 + (l&15)] — a valid MFMA
// A-frag (i=l&15) and B-frag (j=l&15) for v_mfma_f32_16x16x32_f16.
// g_Wt: x-part rows 0..255 (tiles 0..31 gate, 32..47 cand).
// g_Wh: h-part rows 256..511 (same tiling).
__device__ __attribute__((aligned(16))) _Float16 g_Wt[48 * 8 * 64 * 8];
__device__ __attribute__((aligned(16))) _Float16 g_Wh[48 * 8 * 64 * 8];

__global__ __launch_bounds__(512) void prep_wt(
    const float* __restrict__ gk, const float* __restrict__ ck)
{
    const int  blk  = blockIdx.x;        // 0..95
    const bool isH  = blk >= 48;
    const int  ct   = isH ? blk - 48 : blk;
    const int  step = threadIdx.x >> 6;  // 0..7
    const int  lane = threadIdx.x & 63;
    const bool isG  = ct < 32;
    const float* W  = isG ? gk : ck;
    const int  nc   = isG ? 512 : 256;
    const int  col  = (isG ? ct : ct - 32) * 16 + (lane & 15);
    const int  k0   = step * 32 + (lane >> 4) * 8 + (isH ? 256 : 0);
    half8 v;
    #pragma unroll
    for (int j = 0; j < 8; ++j)
        v[j] = (_Float16)W[(size_t)(k0 + j) * nc + col];
    _Float16* dst = isH ? g_Wh : g_Wt;
    *(half8*)&dst[((size_t)(ct * 8 + step) * 64 + lane) * 8] = v;
}

// ============================================================================
// Projection GEMM: proj = x @ W_x (+bias). A = x (i = batch row), B = W
// (j = output col). D: row i = (lane>>4)*4+reg (batch), col j = lane&15.
// Epilogue v2: per p-iteration the block's 8 waves cover a contiguous
// 128-col span (gate cols p*128.. for p<4; cand cols (p-4)*128.. for p>=4).
// Results staged f16 in LDS (reusing xs), then stored as uint4 rows
// (256 B contiguous per 16 lanes) — replaces the 32 B-segment u16 scatter.
// ============================================================================
__global__ __launch_bounds__(512, 2) void proj_mfma(
    const float* __restrict__ x, const float* __restrict__ gb,
    const float* __restrict__ cb,
    u16* pg,                      // aliases d_out: [102400][512] u16
    u16* __restrict__ pc)         // ws: [102400][256] u16
{
    __shared__ __attribute__((aligned(16))) _Float16 xs[64][264]; // also reused as st[64][136]
    _Float16 (*st)[136] = (_Float16(*)[136])&xs[0][0];

    const int tid  = threadIdx.x;
    const int m0   = blockIdx.x * 64;
    const int lane = tid & 63;
    const int w    = tid >> 6;
    const int qr4  = (lane >> 4) * 4;
    const int cl   = lane & 15;

    // ---- stage x tile fp32 -> f16 LDS (coalesced float4 loads) ----
    #pragma unroll
    for (int q = 0; q < 8; ++q) {
        int f = tid + 512 * q;
        int r = f >> 6, c = (f & 63) * 4;
        float4 v = *(const float4*)&x[(size_t)(m0 + r) * 256 + c];
        uint2 p;
        union { _Float16 h[2]; u32 u; } t0, t1;
        t0.h[0] = (_Float16)v.x; t0.h[1] = (_Float16)v.y;
        t1.h[0] = (_Float16)v.z; t1.h[1] = (_Float16)v.w;
        p.x = t0.u; p.y = t1.u;
        *(uint2*)&xs[r][c] = p;
    }
    BARX();

    // ---- A-fragments (x) for the whole block: 128 VGPRs, read once ----
    half8 xf[4][8];
    #pragma unroll
    for (int jt = 0; jt < 4; ++jt)
        #pragma unroll
        for (int kc = 0; kc < 8; ++kc)
            xf[jt][kc] = *(const half8*)&xs[jt * 16 + cl][kc * 32 + (lane >> 4) * 8];

    #pragma unroll 1
    for (int p = 0; p < 6; ++p) {
        const int it = w + 8 * p;       // col tile 0..47 (wave-uniform)
        const _Float16* bp = &g_Wt[(size_t)it * 4096];
        half8 bf[8];
        #pragma unroll
        for (int kc = 0; kc < 8; ++kc)
            bf[kc] = *(const half8*)&bp[(kc * 64 + lane) * 8];

        f32x4 acc[4] = {};
        #pragma unroll
        for (int kc = 0; kc < 8; ++kc)
            #pragma unroll
            for (int jt = 0; jt < 4; ++jt)
                acc[jt] = __builtin_amdgcn_mfma_f32_16x16x32_f16(
                              xf[jt][kc], bf[kc], acc[jt], 0, 0, 0);

        // ---- stage results to LDS (prev iteration's reads drained first) ----
        const int n = it * 16 + cl;     // global output col 0..767
        const float bias = (p < 4) ? gb[n] : cb[n - 512];
        BARX();
        #pragma unroll
        for (int jt = 0; jt < 4; ++jt)
            #pragma unroll
            for (int r = 0; r < 4; ++r)
                st[jt * 16 + qr4 + r][w * 16 + cl] = (_Float16)(acc[jt][r] + bias);
        BARX();

        // ---- cooperative coalesced store: 64 rows x 128 cols (u16) ----
        #pragma unroll
        for (int q = 0; q < 2; ++q) {
            int idx = tid + 512 * q;            // 0..1023
            int row = idx >> 4, seg = idx & 15; // 16 uint4 per row
            uint4 v = *(const uint4*)&st[row][seg * 8];
            if (p < 4)
                *(uint4*)&pg[(size_t)(m0 + row) * 512 + p * 128 + seg * 8] = v;
            else
                *(uint4*)&pc[(size_t)(m0 + row) * 256 + (p - 4) * 128 + seg * 8] = v;
        }
    }
}

// ============================================================================
// Recurrent kernel v4: fixes v3's register-spill catastrophe.
// Residency split: Wr + Wu fragments in registers (128 regs, AGPR-friendly);
// Wc in LDS (128 KB, staged once). ha/ra streamed per-kstep. Raw lgkm-only
// barriers (global ops flow across). Distance-1 prefetch of pg/pc issued
// before the out-stores. 32 blocks x 512 thr, 16 batch rows, 48 MFMA/wave/step.
// ============================================================================
__global__ __launch_bounds__(512) void gru_rec4(
    const int* __restrict__ slen,
    const u16* pg,                 // aliases d_out: [m][512] u16
    const u16* __restrict__ pc,    // ws: [m][256] u16
    float* out)                    // aliases pg (barrier-ordered read-then-write)
{
    __shared__ __attribute__((aligned(16))) _Float16 wc_lds[16 * 8 * 64 * 8]; // 128 KB
    __shared__ _Float16 h_lds[16][264];
    __shared__ _Float16 rh_lds[16][264];

    const int tid  = threadIdx.x;
    const int w    = tid >> 6;       // wave 0..7
    const int lane = tid & 63;
    const int qr   = lane >> 4;      // 0..3
    const int cl   = lane & 15;
    const int b0   = blockIdx.x * 16;
    const int colR0 = 32 * w + cl;

    // ---- stage Wc (g_Wh tiles 32..47, 128 KB) into LDS ----
    {
        const uint4* srcv = (const uint4*)&g_Wh[32 * 8 * 64 * 8];
        uint4* dstv = (uint4*)wc_lds;
        for (int i = tid; i < 8192; i += 512) dstv[i] = srcv[i];
    }

    // ---- persistent register fragments: reset + update ----
    half8 wr[2][8], wu[2][8];
    #pragma unroll
    for (int tt = 0; tt < 2; ++tt)
        #pragma unroll
        for (int s = 0; s < 8; ++s) {
            wr[tt][s] = *(const half8*)&g_Wh[(((size_t)(2 * w + tt) * 8 + s) * 64 + lane) * 8];
            wu[tt][s] = *(const half8*)&g_Wh[(((size_t)(16 + 2 * w + tt) * 8 + s) * 64 + lane) * 8];
        }

    // ---- init h = 0 ----
    for (int i = tid; i < 16 * 264; i += 512)
        ((_Float16*)h_lds)[i] = (_Float16)0.0f;

    int lenr[4];
    #pragma unroll
    for (int r = 0; r < 4; ++r) lenr[r] = slen[b0 + qr * 4 + r];

    const u16* pgp[4]; const u16* pcp[4]; float* outp[4];
    #pragma unroll
    for (int r = 0; r < 4; ++r) {
        size_t m = (size_t)(b0 + qr * 4 + r) * T_;
        pgp[r]  = pg  + m * 512 + colR0;
        pcp[r]  = pc  + m * 256 + colR0;
        outp[r] = out + m * 256 + colR0;
    }

    // ---- prologue prefetch (t = 0) ----
    u16 cr[2][4], cu[2][4], cc[2][4];
    #pragma unroll
    for (int tt = 0; tt < 2; ++tt)
        #pragma unroll
        for (int r = 0; r < 4; ++r) {
            cr[tt][r] = __builtin_nontemporal_load(pgp[r] + tt * 16);
            cu[tt][r] = __builtin_nontemporal_load(pgp[r] + 256 + tt * 16);
            cc[tt][r] = __builtin_nontemporal_load(pcp[r] + tt * 16);
        }

    float hold[2][4] = {};
    float uu[2][4];

    for (int t = 0; t < T_; ++t) {
        BARX();                                   // A: h(t-1) LDS writes visible

        // ---- gates: h @ [Wr|Wu], ha streamed per-kstep ----
        f32x4 ar0 = {}, ar1 = {}, au0 = {}, au1 = {};
        #pragma unroll
        for (int s = 0; s < 8; ++s) {
            half8 ha = *(const half8*)&h_lds[cl][s * 32 + qr * 8];
            ar0 = __builtin_amdgcn_mfma_f32_16x16x32_f16(ha, wr[0][s], ar0, 0, 0, 0);
            au0 = __builtin_amdgcn_mfma_f32_16x16x32_f16(ha, wu[0][s], au0, 0, 0, 0);
            ar1 = __builtin_amdgcn_mfma_f32_16x16x32_f16(ha, wr[1][s], ar1, 0, 0, 0);
            au1 = __builtin_amdgcn_mfma_f32_16x16x32_f16(ha, wu[1][s], au1, 0, 0, 0);
        }

        #pragma unroll
        for (int r = 0; r < 4; ++r) {
            float rv0 = sigmoid_f(ar0[r] + f16f(cr[0][r]));
            float rv1 = sigmoid_f(ar1[r] + f16f(cr[1][r]));
            uu[0][r] = sigmoid_f(au0[r] + f16f(cu[0][r]));
            uu[1][r] = sigmoid_f(au1[r] + f16f(cu[1][r]));
            rh_lds[qr * 4 + r][colR0]      = (_Float16)(rv0 * hold[0][r]);
            rh_lds[qr * 4 + r][colR0 + 16] = (_Float16)(rv1 * hold[1][r]);
        }

        BARX();                                   // B: rh visible

        // ---- prefetch t+1 BEFORE the out-stores (FIFO vmcnt) ----
        const int dg = (t + 1 < T_) ? 512 : 0;
        const int dc = (t + 1 < T_) ? 256 : 0;
        u16 nr[2][4], nu[2][4], nc[2][4];
        #pragma unroll
        for (int tt = 0; tt < 2; ++tt)
            #pragma unroll
            for (int r = 0; r < 4; ++r) {
                nr[tt][r] = __builtin_nontemporal_load(pgp[r] + dg + tt * 16);
                nu[tt][r] = __builtin_nontemporal_load(pgp[r] + dg + 256 + tt * 16);
                nc[tt][r] = __builtin_nontemporal_load(pcp[r] + dc + tt * 16);
            }

        // ---- candidate: (r*h) @ Wc, Wc streamed from LDS ----
        f32x4 c00 = {}, c01 = {}, c10 = {}, c11 = {};
        #pragma unroll
        for (int s2 = 0; s2 < 4; ++s2) {
            const int s = 2 * s2;
            half8 ra0 = *(const half8*)&rh_lds[cl][s * 32 + qr * 8];
            half8 ra1 = *(const half8*)&rh_lds[cl][(s + 1) * 32 + qr * 8];
            half8 w00 = *(const half8*)&wc_lds[(((2 * w + 0) * 8 + s) * 64 + lane) * 8];
            half8 w01 = *(const half8*)&wc_lds[(((2 * w + 1) * 8 + s) * 64 + lane) * 8];
            half8 w10 = *(const half8*)&wc_lds[(((2 * w + 0) * 8 + s + 1) * 64 + lane) * 8];
            half8 w11 = *(const half8*)&wc_lds[(((2 * w + 1) * 8 + s + 1) * 64 + lane) * 8];
            c00 = __builtin_amdgcn_mfma_f32_16x16x32_f16(ra0, w00, c00, 0, 0, 0);
            c01 = __builtin_amdgcn_mfma_f32_16x16x32_f16(ra0, w01, c01, 0, 0, 0);
            c10 = __builtin_amdgcn_mfma_f32_16x16x32_f16(ra1, w10, c10, 0, 0, 0);
            c11 = __builtin_amdgcn_mfma_f32_16x16x32_f16(ra1, w11, c11, 0, 0, 0);
        }

        #pragma unroll
        for (int r = 0; r < 4; ++r) {
            float cd0 = tanh_f(c00[r] + c10[r] + f16f(cc[0][r]));
            float cd1 = tanh_f(c01[r] + c11[r] + f16f(cc[1][r]));
            float u0 = uu[0][r], u1 = uu[1][r];
            float hn0 = u0 * hold[0][r] + (1.0f - u0) * cd0;
            float hn1 = u1 * hold[1][r] + (1.0f - u1) * cd1;
            bool valid = (t < lenr[r]);
            __builtin_nontemporal_store(valid ? hn0 : 0.0f, outp[r]);
            __builtin_nontemporal_store(valid ? hn1 : 0.0f, outp[r] + 16);
            if (valid) {
                hold[0][r] = hn0; hold[1][r] = hn1;
                h_lds[qr * 4 + r][colR0]      = (_Float16)hn0;
                h_lds[qr * 4 + r][colR0 + 16] = (_Float16)hn1;
            }
        }

        #pragma unroll
        for (int r = 0; r < 4; ++r) { pgp[r] += 512; pcp[r] += 256; outp[r] += 256; }
        #pragma unroll
        for (int tt = 0; tt < 2; ++tt)
            #pragma unroll
            for (int r = 0; r < 4; ++r) {
                cr[tt][r] = nr[tt][r]; cu[tt][r] = nu[tt][r]; cc[tt][r] = nc[tt][r];
            }
    }
}

extern "C" void kernel_launch(void* const* d_in, const int* in_sizes, int n_in,
                              void* d_out, int out_size, void* d_ws, size_t ws_size,
                              hipStream_t stream) {
    const float* x    = (const float*)d_in[0];
    const int*   slen = (const int*)  d_in[1];
    const float* gk   = (const float*)d_in[2];
    const float* gb   = (const float*)d_in[3];
    const float* ck   = (const float*)d_in[4];
    const float* cb   = (const float*)d_in[5];
    float* out = (float*)d_out;
    u16*   pg  = (u16*)d_out;   // [102400][512] u16 == 104.86 MB == out size
    u16*   pc  = (u16*)d_ws;    // 52.4 MB cand x-proj

    prep_wt<<<dim3(96), 512, 0, stream>>>(gk, ck);
    proj_mfma<<<dim3(1600), 512, 0, stream>>>(x, gb, cb, pg, pc);
    gru_rec4<<<dim3(32), 512, 0, stream>>>(slen, pg, pc, out);
}

// Round 5
// 994.654 us; speedup vs baseline: 1.0723x; 1.0003x over previous
//
#include <hip/hip_runtime.h>
#include <math.h>

#define B_ 512
#define T_ 200
#define D_ 256
#define H_ 256

typedef unsigned int   u32;
typedef unsigned short u16;
typedef _Float16 half8 __attribute__((ext_vector_type(8)));
typedef float f32x4 __attribute__((ext_vector_type(4)));
typedef u32 u32x2 __attribute__((ext_vector_type(2)));   // clang vector: OK for nontemporal builtins

__device__ __forceinline__ float sigmoid_f(float x) { return 1.0f / (1.0f + __expf(-x)); }
__device__ __forceinline__ float tanh_f(float x)    { return 1.0f - 2.0f / (__expf(2.0f * x) + 1.0f); }
__device__ __forceinline__ u16 f16b(float x) { union { _Float16 h; u16 u; } r; r.h = (_Float16)x; return r.u; }
__device__ __forceinline__ float f16f(u16 v) { union { u16 u; _Float16 h; } r; r.u = v; return (float)r.h; }

// Raw barrier: drain LDS ops only; global loads/stores stay in flight.
#define BARX() asm volatile("s_waitcnt lgkmcnt(0)\n\ts_barrier" ::: "memory")

// Fragment-major f16 weights: [tile][kstep][lane][8]; lane l holds
// W[k = kstep*32 + (l>>4)*8 + 0..7][col = tile*16 + (l&15)].
// g_Wt: x-part rows 0..255 (tiles 0..15 reset, 16..31 update, 32..47 cand).
// g_Wh: h-part rows 256..511 (same tiling).
__device__ __attribute__((aligned(16))) _Float16 g_Wt[48 * 8 * 64 * 8];
__device__ __attribute__((aligned(16))) _Float16 g_Wh[48 * 8 * 64 * 8];

__global__ __launch_bounds__(512) void prep_wt(
    const float* __restrict__ gk, const float* __restrict__ ck)
{
    const int  blk  = blockIdx.x;        // 0..95
    const bool isH  = blk >= 48;
    const int  ct   = isH ? blk - 48 : blk;
    const int  step = threadIdx.x >> 6;
    const int  lane = threadIdx.x & 63;
    const bool isG  = ct < 32;
    const float* W  = isG ? gk : ck;
    const int  nc   = isG ? 512 : 256;
    const int  col  = (isG ? ct : ct - 32) * 16 + (lane & 15);
    const int  k0   = step * 32 + (lane >> 4) * 8 + (isH ? 256 : 0);
    half8 v;
    #pragma unroll
    for (int j = 0; j < 8; ++j)
        v[j] = (_Float16)W[(size_t)(k0 + j) * nc + col];
    _Float16* dst = isH ? g_Wh : g_Wt;
    *(half8*)&dst[((size_t)(ct * 8 + step) * 64 + lane) * 8] = v;
}

// ============================================================================
// Projection GEMM -> PACKED PERMUTED layouts for the recurrent kernel:
//   pgI: [m][256] u32, entry e(c) = (c>>6)*64 + (c&15)*4 + ((c>>4)&3)
//        holds (reset_c | update_c<<16) as f16 pair (gate cols c, 256+c).
//   pcI: [m][256] u16, same permutation, cand col c.
// This makes the rec kernel's per-step prefetch 4 dwordx2 + 4 dword.
// Double-buffered LDS staging; all global stores are coalesced uint4.
// ============================================================================
__global__ __launch_bounds__(512, 2) void proj_mfma(
    const float* __restrict__ x, const float* __restrict__ gb,
    const float* __restrict__ cb,
    u32* pgI,                     // aliases d_out: [102400][256] u32
    u16* __restrict__ pcI)        // ws: [102400][256] u16
{
    // smem[0] overlays the x-staging buffer (same 33792 B footprint each).
    __shared__ __attribute__((aligned(16))) u32 smem[2][64][132];
    _Float16 (*xs)[264] = (_Float16(*)[264])&smem[0][0][0];

    const int tid  = threadIdx.x;
    const int m0   = blockIdx.x * 64;
    const int lane = tid & 63;
    const int w    = tid >> 6;
    const int qr4  = (lane >> 4) * 4;
    const int cl   = lane & 15;
    // staged entry offset (independent of p): le = (w>>2)*64 + cl*4 + (w&3)
    const int le   = (w >> 2) * 64 + cl * 4 + (w & 3);

    // ---- stage x tile fp32 -> f16 LDS ----
    #pragma unroll
    for (int q = 0; q < 8; ++q) {
        int f = tid + 512 * q;
        int r = f >> 6, c = (f & 63) * 4;
        float4 v = *(const float4*)&x[(size_t)(m0 + r) * 256 + c];
        uint2 p;
        union { _Float16 h[2]; u32 u; } t0, t1;
        t0.h[0] = (_Float16)v.x; t0.h[1] = (_Float16)v.y;
        t1.h[0] = (_Float16)v.z; t1.h[1] = (_Float16)v.w;
        p.x = t0.u; p.y = t1.u;
        *(uint2*)&xs[r][c] = p;
    }
    BARX();

    // ---- A-fragments (x) for the whole block ----
    half8 xf[4][8];
    #pragma unroll
    for (int jt = 0; jt < 4; ++jt)
        #pragma unroll
        for (int kc = 0; kc < 8; ++kc)
            xf[jt][kc] = *(const half8*)&xs[jt * 16 + cl][kc * 32 + (lane >> 4) * 8];
    BARX();   // xs dead; smem[0] may now be overwritten

    #pragma unroll 1
    for (int p = 0; p < 6; ++p) {
        const int it = w + 8 * p;       // tile 0..47 (wave-uniform)
        const _Float16* bp = &g_Wt[(size_t)it * 4096];
        half8 bf[8];
        #pragma unroll
        for (int kc = 0; kc < 8; ++kc)
            bf[kc] = *(const half8*)&bp[(kc * 64 + lane) * 8];

        f32x4 acc[4] = {};
        #pragma unroll
        for (int kc = 0; kc < 8; ++kc)
            #pragma unroll
            for (int jt = 0; jt < 4; ++jt)
                acc[jt] = __builtin_amdgcn_mfma_f32_16x16x32_f16(
                              xf[jt][kc], bf[kc], acc[jt], 0, 0, 0);

        const int n    = it * 16 + cl;          // output col 0..767
        const float bias = (p < 4) ? gb[n] : cb[n - 512];
        const int buf  = p & 1;
        u16* s16 = (u16*)&smem[buf][0][0];

        if (p < 2) {            // reset -> low halves
            #pragma unroll
            for (int jt = 0; jt < 4; ++jt)
                #pragma unroll
                for (int r = 0; r < 4; ++r)
                    s16[(jt * 16 + qr4 + r) * 264 + le * 2] = f16b(acc[jt][r] + bias);
        } else if (p < 4) {     // update -> high halves
            #pragma unroll
            for (int jt = 0; jt < 4; ++jt)
                #pragma unroll
                for (int r = 0; r < 4; ++r)
                    s16[(jt * 16 + qr4 + r) * 264 + le * 2 + 1] = f16b(acc[jt][r] + bias);
            BARX();
            // coop store: 64 rows x 128 u32 -> pgI cols [128*buf, +128)
            #pragma unroll
            for (int q = 0; q < 4; ++q) {
                int idx = tid + 512 * q;           // 0..2047
                int row = idx >> 5, seg = idx & 31;
                uint4 v = *(const uint4*)&smem[buf][row][seg * 4];
                *(uint4*)&pgI[(size_t)(m0 + row) * 256 + 128 * buf + seg * 4] = v;
            }
        } else {                // cand -> u16 entries
            #pragma unroll
            for (int jt = 0; jt < 4; ++jt)
                #pragma unroll
                for (int r = 0; r < 4; ++r)
                    s16[(jt * 16 + qr4 + r) * 264 + le] = f16b(acc[jt][r] + bias);
            BARX();
            // coop store: 64 rows x 128 u16 -> pcI cols [128*buf, +128)
            #pragma unroll
            for (int q = 0; q < 2; ++q) {
                int idx = tid + 512 * q;           // 0..1023
                int row = idx >> 4, seg = idx & 15;
                uint4 v = *(const uint4*)((const u16*)&smem[buf][row][0] + seg * 8);
                *(uint4*)&pcI[(size_t)(m0 + row) * 256 + 128 * buf + seg * 8] = v;
            }
        }
        if (p == 2 || p == 3 || p == 4) BARX();   // buffer free for reuse
    }
}

// ============================================================================
// Recurrent kernel v5: spill-proof register budget (target <=256/wave).
// 32 blocks x 512 thr (8 waves, 2/SIMD), 16 batch rows, all 256 cols.
// Wave w owns tiles {2w,2w+1} of each of R,U,C: 48 half8 = 192 weight regs.
// Gates as two passes (R then U) to cap live accs at 8 regs. Packed
// prefetch: 4 dwordx2 (pgI) + 4 dword (pcI) per thread per step.
// 2 lgkm-only barriers/step; h/rh in padded LDS.
// ============================================================================
__global__ __launch_bounds__(512, 2) void gru_rec5(
    const int* __restrict__ slen,
    const u32* pgI,                // aliases d_out: [m][256] u32 permuted
    const u16* __restrict__ pcI,   // ws: [m][256] u16 permuted
    float* out)                    // aliases pgI (load-before-store per step)
{
    __shared__ _Float16 h_lds[16][264];
    __shared__ _Float16 rh_lds[16][264];

    const int tid  = threadIdx.x;
    const int w    = tid >> 6;       // 0..7
    const int lane = tid & 63;
    const int qr   = lane >> 4;
    const int cl   = lane & 15;
    const int b0   = blockIdx.x * 16;

    // ---- weight fragments: 2 tiles each of R, U, C = 192 regs ----
    half8 wR[2][8], wU[2][8], wC[2][8];
    #pragma unroll
    for (int tt = 0; tt < 2; ++tt)
        #pragma unroll
        for (int s = 0; s < 8; ++s) {
            wR[tt][s] = *(const half8*)&g_Wh[(((size_t)(2 * w + tt) * 8 + s) * 64 + lane) * 8];
            wU[tt][s] = *(const half8*)&g_Wh[(((size_t)(16 + 2 * w + tt) * 8 + s) * 64 + lane) * 8];
            wC[tt][s] = *(const half8*)&g_Wh[(((size_t)(32 + 2 * w + tt) * 8 + s) * 64 + lane) * 8];
        }

    for (int i = tid; i < 16 * 264; i += 512)
        ((_Float16*)h_lds)[i] = (_Float16)0.0f;

    // seq lens packed (values <= 200 fit u8)
    u32 lenp = 0;
    #pragma unroll
    for (int r = 0; r < 4; ++r)
        lenp |= ((u32)slen[b0 + qr * 4 + r] & 255u) << (8 * r);

    const u32 eG = (u32)((w >> 1) * 64 + cl * 4 + 2 * (w & 1)); // packed entry base
    const u32 cO = (u32)(32 * w + cl);                          // out col base
    u32 rowT[4];
    #pragma unroll
    for (int r = 0; r < 4; ++r)
        rowT[r] = (u32)(b0 + qr * 4 + r) * (u32)(T_ * 256);

    float hold[2][4] = {};
    float uu[2][4];

    // ---- prologue prefetch (t=0) ----
    u32x2 cg[4]; u32 cc[4];
    #pragma unroll
    for (int r = 0; r < 4; ++r) {
        cg[r] = __builtin_nontemporal_load((const u32x2*)(pgI + rowT[r] + eG));
        cc[r] = __builtin_nontemporal_load((const u32*)(pcI + rowT[r] + eG));
    }

    for (int t = 0; t < T_; ++t) {
        const u32 tb = (u32)t * 256u;
        const u32 tn = (t + 1 < T_) ? tb + 256u : tb;   // last-step re-read is discarded

        BARX();                                   // A: h(t-1) visible

        // ---- reset pass ----
        f32x4 aR0 = {}, aR1 = {};
        #pragma unroll
        for (int s = 0; s < 8; ++s) {
            half8 ha = *(const half8*)&h_lds[cl][s * 32 + qr * 8];
            aR0 = __builtin_amdgcn_mfma_f32_16x16x32_f16(ha, wR[0][s], aR0, 0, 0, 0);
            aR1 = __builtin_amdgcn_mfma_f32_16x16x32_f16(ha, wR[1][s], aR1, 0, 0, 0);
        }
        #pragma unroll
        for (int r = 0; r < 4; ++r) {
            float rv0 = sigmoid_f(aR0[r] + f16f((u16)(cg[r].x & 0xffffu)));
            float rv1 = sigmoid_f(aR1[r] + f16f((u16)(cg[r].y & 0xffffu)));
            rh_lds[qr * 4 + r][32 * w + cl]      = (_Float16)(rv0 * hold[0][r]);
            rh_lds[qr * 4 + r][32 * w + 16 + cl] = (_Float16)(rv1 * hold[1][r]);
        }

        // ---- update pass ----
        f32x4 aU0 = {}, aU1 = {};
        #pragma unroll
        for (int s = 0; s < 8; ++s) {
            half8 ha = *(const half8*)&h_lds[cl][s * 32 + qr * 8];
            aU0 = __builtin_amdgcn_mfma_f32_16x16x32_f16(ha, wU[0][s], aU0, 0, 0, 0);
            aU1 = __builtin_amdgcn_mfma_f32_16x16x32_f16(ha, wU[1][s], aU1, 0, 0, 0);
        }
        #pragma unroll
        for (int r = 0; r < 4; ++r) {
            uu[0][r] = sigmoid_f(aU0[r] + f16f((u16)(cg[r].x >> 16)));
            uu[1][r] = sigmoid_f(aU1[r] + f16f((u16)(cg[r].y >> 16)));
        }

        // ---- prefetch gates t+1 (cg consumed; regs reusable) ----
        u32x2 ng[4];
        #pragma unroll
        for (int r = 0; r < 4; ++r)
            ng[r] = __builtin_nontemporal_load((const u32x2*)(pgI + rowT[r] + tn + eG));

        BARX();                                   // B: rh visible

        // ---- candidate ----
        f32x4 aC0 = {}, aC1 = {};
        #pragma unroll
        for (int s = 0; s < 8; ++s) {
            half8 ra = *(const half8*)&rh_lds[cl][s * 32 + qr * 8];
            aC0 = __builtin_amdgcn_mfma_f32_16x16x32_f16(ra, wC[0][s], aC0, 0, 0, 0);
            aC1 = __builtin_amdgcn_mfma_f32_16x16x32_f16(ra, wC[1][s], aC1, 0, 0, 0);
        }

        // ---- prefetch cand t+1 ----
        u32 nc[4];
        #pragma unroll
        for (int r = 0; r < 4; ++r)
            nc[r] = __builtin_nontemporal_load((const u32*)(pcI + rowT[r] + tn + eG));

        // ---- finalize + out stores (issued AFTER the prefetch loads) ----
        #pragma unroll
        for (int r = 0; r < 4; ++r) {
            float cd0 = tanh_f(aC0[r] + f16f((u16)(cc[r] & 0xffffu)));
            float cd1 = tanh_f(aC1[r] + f16f((u16)(cc[r] >> 16)));
            float u0 = uu[0][r], u1 = uu[1][r];
            float hn0 = u0 * hold[0][r] + (1.0f - u0) * cd0;
            float hn1 = u1 * hold[1][r] + (1.0f - u1) * cd1;
            bool valid = t < (int)((lenp >> (8 * r)) & 255u);
            __builtin_nontemporal_store(valid ? hn0 : 0.0f, out + rowT[r] + tb + cO);
            __builtin_nontemporal_store(valid ? hn1 : 0.0f, out + rowT[r] + tb + cO + 16);
            if (valid) {
                hold[0][r] = hn0; hold[1][r] = hn1;
                h_lds[qr * 4 + r][32 * w + cl]      = (_Float16)hn0;
                h_lds[qr * 4 + r][32 * w + 16 + cl] = (_Float16)hn1;
            }
        }

        #pragma unroll
        for (int r = 0; r < 4; ++r) { cg[r] = ng[r]; cc[r] = nc[r]; }
    }
}

extern "C" void kernel_launch(void* const* d_in, const int* in_sizes, int n_in,
                              void* d_out, int out_size, void* d_ws, size_t ws_size,
                              hipStream_t stream) {
    const float* x    = (const float*)d_in[0];
    const int*   slen = (const int*)  d_in[1];
    const float* gk   = (const float*)d_in[2];
    const float* gb   = (const float*)d_in[3];
    const float* ck   = (const float*)d_in[4];
    const float* cb   = (const float*)d_in[5];
    float* out = (float*)d_out;
    u32*   pgI = (u32*)d_out;   // [102400][256] u32 == 104.86 MB == out size
    u16*   pcI = (u16*)d_ws;    // [102400][256] u16 == 52.4 MB

    prep_wt<<<dim3(96), 512, 0, stream>>>(gk, ck);
    proj_mfma<<<dim3(1600), 512, 0, stream>>>(x, gb, cb, pgI, pcI);
    gru_rec5<<<dim3(32), 512, 0, stream>>>(slen, pgI, pcI, out);
}

// Round 6
// 980.962 us; speedup vs baseline: 1.0873x; 1.0140x over previous
//
#include <hip/hip_runtime.h>
#include <math.h>

#define B_ 512
#define T_ 200
#define D_ 256
#define H_ 256

typedef unsigned int   u32;
typedef unsigned short u16;
typedef _Float16 half8 __attribute__((ext_vector_type(8)));
typedef float f32x4 __attribute__((ext_vector_type(4)));
typedef u32 u32x2 __attribute__((ext_vector_type(2)));

__device__ __forceinline__ float sigmoid_f(float x) { return 1.0f / (1.0f + __expf(-x)); }
__device__ __forceinline__ float tanh_f(float x)    { return 1.0f - 2.0f / (__expf(2.0f * x) + 1.0f); }
__device__ __forceinline__ u16 f16b(float x) { union { _Float16 h; u16 u; } r; r.h = (_Float16)x; return r.u; }
__device__ __forceinline__ float f16f(u16 v) { union { u16 u; _Float16 h; } r; r.u = v; return (float)r.h; }

// Raw barrier: drain LDS ops only; global loads/stores stay in flight.
#define BARX() asm volatile("s_waitcnt lgkmcnt(0)\n\ts_barrier" ::: "memory")

// Fragment-major f16 weights: [tile][kstep][lane][8]; lane l holds
// W[k = kstep*32 + (l>>4)*8 + 0..7][col = tile*16 + (l&15)].
// g_Wt: x-part rows 0..255 (tiles 0..15 reset, 16..31 update, 32..47 cand).
// g_Wh: h-part rows 256..511 (same tiling).
__device__ __attribute__((aligned(16))) _Float16 g_Wt[48 * 8 * 64 * 8];
__device__ __attribute__((aligned(16))) _Float16 g_Wh[48 * 8 * 64 * 8];

__global__ __launch_bounds__(512) void prep_wt(
    const float* __restrict__ gk, const float* __restrict__ ck)
{
    const int  blk  = blockIdx.x;        // 0..95
    const bool isH  = blk >= 48;
    const int  ct   = isH ? blk - 48 : blk;
    const int  step = threadIdx.x >> 6;
    const int  lane = threadIdx.x & 63;
    const bool isG  = ct < 32;
    const float* W  = isG ? gk : ck;
    const int  nc   = isG ? 512 : 256;
    const int  col  = (isG ? ct : ct - 32) * 16 + (lane & 15);
    const int  k0   = step * 32 + (lane >> 4) * 8 + (isH ? 256 : 0);
    half8 v;
    #pragma unroll
    for (int j = 0; j < 8; ++j)
        v[j] = (_Float16)W[(size_t)(k0 + j) * nc + col];
    _Float16* dst = isH ? g_Wh : g_Wt;
    *(half8*)&dst[((size_t)(ct * 8 + step) * 64 + lane) * 8] = v;
}

// ============================================================================
// Projection GEMM -> packed permuted layouts (unchanged math from R4/R5):
//   pgI: [m][256] u32, entry e(c) = (c>>6)*64 + (c&15)*4 + ((c>>4)&3)
//        holds (reset_c | update_c<<16); pcI: [m][256] u16, same perm.
// NEW: amdgpu_waves_per_eu(2,2) pins the allocator at a 256-reg budget —
// the ~190-reg working set (128 xf + 32 bf + acc) no longer spills.
// ============================================================================
__global__ __launch_bounds__(512) __attribute__((amdgpu_waves_per_eu(2, 2)))
void proj_mfma(
    const float* __restrict__ x, const float* __restrict__ gb,
    const float* __restrict__ cb,
    u32* pgI,                     // aliases d_out: [102400][256] u32
    u16* __restrict__ pcI)        // ws: [102400][256] u16
{
    __shared__ __attribute__((aligned(16))) u32 smem[2][64][132];
    _Float16 (*xs)[264] = (_Float16(*)[264])&smem[0][0][0];

    const int tid  = threadIdx.x;
    const int m0   = blockIdx.x * 64;
    const int lane = tid & 63;
    const int w    = tid >> 6;
    const int qr4  = (lane >> 4) * 4;
    const int cl   = lane & 15;
    const int le   = (w >> 2) * 64 + cl * 4 + (w & 3);

    #pragma unroll
    for (int q = 0; q < 8; ++q) {
        int f = tid + 512 * q;
        int r = f >> 6, c = (f & 63) * 4;
        float4 v = *(const float4*)&x[(size_t)(m0 + r) * 256 + c];
        uint2 p;
        union { _Float16 h[2]; u32 u; } t0, t1;
        t0.h[0] = (_Float16)v.x; t0.h[1] = (_Float16)v.y;
        t1.h[0] = (_Float16)v.z; t1.h[1] = (_Float16)v.w;
        p.x = t0.u; p.y = t1.u;
        *(uint2*)&xs[r][c] = p;
    }
    BARX();

    half8 xf[4][8];
    #pragma unroll
    for (int jt = 0; jt < 4; ++jt)
        #pragma unroll
        for (int kc = 0; kc < 8; ++kc)
            xf[jt][kc] = *(const half8*)&xs[jt * 16 + cl][kc * 32 + (lane >> 4) * 8];
    BARX();   // xs dead; smem[0] may now be overwritten

    #pragma unroll 1
    for (int p = 0; p < 6; ++p) {
        const int it = w + 8 * p;
        const _Float16* bp = &g_Wt[(size_t)it * 4096];
        half8 bf[8];
        #pragma unroll
        for (int kc = 0; kc < 8; ++kc)
            bf[kc] = *(const half8*)&bp[(kc * 64 + lane) * 8];

        f32x4 acc[4] = {};
        #pragma unroll
        for (int kc = 0; kc < 8; ++kc)
            #pragma unroll
            for (int jt = 0; jt < 4; ++jt)
                acc[jt] = __builtin_amdgcn_mfma_f32_16x16x32_f16(
                              xf[jt][kc], bf[kc], acc[jt], 0, 0, 0);

        const int n    = it * 16 + cl;
        const float bias = (p < 4) ? gb[n] : cb[n - 512];
        const int buf  = p & 1;
        u16* s16 = (u16*)&smem[buf][0][0];

        if (p < 2) {            // reset -> low halves
            #pragma unroll
            for (int jt = 0; jt < 4; ++jt)
                #pragma unroll
                for (int r = 0; r < 4; ++r)
                    s16[(jt * 16 + qr4 + r) * 264 + le * 2] = f16b(acc[jt][r] + bias);
        } else if (p < 4) {     // update -> high halves
            #pragma unroll
            for (int jt = 0; jt < 4; ++jt)
                #pragma unroll
                for (int r = 0; r < 4; ++r)
                    s16[(jt * 16 + qr4 + r) * 264 + le * 2 + 1] = f16b(acc[jt][r] + bias);
            BARX();
            #pragma unroll
            for (int q = 0; q < 4; ++q) {
                int idx = tid + 512 * q;
                int row = idx >> 5, seg = idx & 31;
                uint4 v = *(const uint4*)&smem[buf][row][seg * 4];
                *(uint4*)&pgI[(size_t)(m0 + row) * 256 + 128 * buf + seg * 4] = v;
            }
        } else {                // cand -> u16 entries
            #pragma unroll
            for (int jt = 0; jt < 4; ++jt)
                #pragma unroll
                for (int r = 0; r < 4; ++r)
                    s16[(jt * 16 + qr4 + r) * 264 + le] = f16b(acc[jt][r] + bias);
            BARX();
            #pragma unroll
            for (int q = 0; q < 2; ++q) {
                int idx = tid + 512 * q;
                int row = idx >> 4, seg = idx & 15;
                uint4 v = *(const uint4*)((const u16*)&smem[buf][row][0] + seg * 8);
                *(uint4*)&pcI[(size_t)(m0 + row) * 256 + 128 * buf + seg * 8] = v;
            }
        }
        if (p == 2 || p == 3 || p == 4) BARX();
    }
}

// ============================================================================
// Recurrent kernel v6: SPILL ELIMINATION.
//  - amdgpu_waves_per_eu(2,2): allocator budget pinned at 256 regs/wave;
//    previously the backend targeted 4 waves/EU (VGPR_Count=128) and spilled
//    the 192-reg weight set to scratch, reloading it every timestep.
//  - Working set trimmed to ~235 peak: single-buffered gate prefetch
//    (reload right after consumption), cand proj loaded in-phase after
//    barrier B, R finalized before U-pass (acc peak 8).
//  - All loads/stores plain (no nontemporal): L3-served, no NT slow-ack.
// 32 blocks x 512 thr (8 waves), 16 batch rows, 2 lgkm-only barriers/step.
// ============================================================================
__global__ __launch_bounds__(512) __attribute__((amdgpu_waves_per_eu(2, 2)))
void gru_rec6(
    const int* __restrict__ slen,
    const u32* pgI,                // aliases d_out: [m][256] u32 permuted
    const u16* __restrict__ pcI,   // ws: [m][256] u16 permuted
    float* out)                    // aliases pgI (row t stored after row t+1 read)
{
    __shared__ _Float16 h_lds[16][264];
    __shared__ _Float16 rh_lds[16][264];

    const int tid  = threadIdx.x;
    const int w    = tid >> 6;       // 0..7
    const int lane = tid & 63;
    const int qr   = lane >> 4;
    const int cl   = lane & 15;
    const int b0   = blockIdx.x * 16;

    // ---- weight fragments: 2 tiles each of R, U, C = 192 regs ----
    half8 wR[2][8], wU[2][8], wC[2][8];
    #pragma unroll
    for (int tt = 0; tt < 2; ++tt)
        #pragma unroll
        for (int s = 0; s < 8; ++s) {
            wR[tt][s] = *(const half8*)&g_Wh[(((size_t)(2 * w + tt) * 8 + s) * 64 + lane) * 8];
            wU[tt][s] = *(const half8*)&g_Wh[(((size_t)(16 + 2 * w + tt) * 8 + s) * 64 + lane) * 8];
            wC[tt][s] = *(const half8*)&g_Wh[(((size_t)(32 + 2 * w + tt) * 8 + s) * 64 + lane) * 8];
        }

    for (int i = tid; i < 16 * 264; i += 512)
        ((_Float16*)h_lds)[i] = (_Float16)0.0f;

    // seq lens packed (values <= 200 fit u8)
    u32 lenp = 0;
    #pragma unroll
    for (int r = 0; r < 4; ++r)
        lenp |= ((u32)slen[b0 + qr * 4 + r] & 255u) << (8 * r);

    const u32 eG = (u32)((w >> 1) * 64 + cl * 4 + 2 * (w & 1)); // packed entry base
    const u32 cO = (u32)(32 * w + cl);                          // out col base
    u32 rowT[4];
    #pragma unroll
    for (int r = 0; r < 4; ++r)
        rowT[r] = (u32)(b0 + qr * 4 + r) * (u32)(T_ * 256);

    float hold[2][4] = {};
    float uu[2][4];

    // ---- prologue: gate proj for t=0 (single buffer) ----
    u32x2 cg[4];
    #pragma unroll
    for (int r = 0; r < 4; ++r)
        cg[r] = *(const u32x2*)(pgI + rowT[r] + eG);

    for (int t = 0; t < T_; ++t) {
        const u32 tb = (u32)t * 256u;
        const u32 tn = (t + 1 < T_) ? tb + 256u : tb;   // last-step re-read discarded

        BARX();                                   // A: h(t-1) visible

        // ---- reset pass: 8 ds_read + 16 MFMA ----
        f32x4 aR0 = {}, aR1 = {};
        #pragma unroll
        for (int s = 0; s < 8; ++s) {
            half8 ha = *(const half8*)&h_lds[cl][s * 32 + qr * 8];
            aR0 = __builtin_amdgcn_mfma_f32_16x16x32_f16(ha, wR[0][s], aR0, 0, 0, 0);
            aR1 = __builtin_amdgcn_mfma_f32_16x16x32_f16(ha, wR[1][s], aR1, 0, 0, 0);
        }
        #pragma unroll
        for (int r = 0; r < 4; ++r) {
            float rv0 = sigmoid_f(aR0[r] + f16f((u16)(cg[r].x & 0xffffu)));
            float rv1 = sigmoid_f(aR1[r] + f16f((u16)(cg[r].y & 0xffffu)));
            rh_lds[qr * 4 + r][32 * w + cl]      = (_Float16)(rv0 * hold[0][r]);
            rh_lds[qr * 4 + r][32 * w + 16 + cl] = (_Float16)(rv1 * hold[1][r]);
        }

        // ---- update pass: 8 ds_read + 16 MFMA ----
        f32x4 aU0 = {}, aU1 = {};
        #pragma unroll
        for (int s = 0; s < 8; ++s) {
            half8 ha = *(const half8*)&h_lds[cl][s * 32 + qr * 8];
            aU0 = __builtin_amdgcn_mfma_f32_16x16x32_f16(ha, wU[0][s], aU0, 0, 0, 0);
            aU1 = __builtin_amdgcn_mfma_f32_16x16x32_f16(ha, wU[1][s], aU1, 0, 0, 0);
        }
        #pragma unroll
        for (int r = 0; r < 4; ++r) {
            uu[0][r] = sigmoid_f(aU0[r] + f16f((u16)(cg[r].x >> 16)));
            uu[1][r] = sigmoid_f(aU1[r] + f16f((u16)(cg[r].y >> 16)));
        }

        // ---- reload gate proj for t+1 into the SAME regs (consumed above) ----
        #pragma unroll
        for (int r = 0; r < 4; ++r)
            cg[r] = *(const u32x2*)(pgI + rowT[r] + tn + eG);

        BARX();                                   // B: rh visible

        // ---- cand proj for THIS step (latency covered by ds+MFMA below) ----
        u32 cc[4];
        #pragma unroll
        for (int r = 0; r < 4; ++r)
            cc[r] = *(const u32*)(pcI + rowT[r] + tb + eG);

        // ---- candidate: 8 ds_read + 16 MFMA ----
        f32x4 aC0 = {}, aC1 = {};
        #pragma unroll
        for (int s = 0; s < 8; ++s) {
            half8 ra = *(const half8*)&rh_lds[cl][s * 32 + qr * 8];
            aC0 = __builtin_amdgcn_mfma_f32_16x16x32_f16(ra, wC[0][s], aC0, 0, 0, 0);
            aC1 = __builtin_amdgcn_mfma_f32_16x16x32_f16(ra, wC[1][s], aC1, 0, 0, 0);
        }

        // ---- finalize + stores ----
        #pragma unroll
        for (int r = 0; r < 4; ++r) {
            float cd0 = tanh_f(aC0[r] + f16f((u16)(cc[r] & 0xffffu)));
            float cd1 = tanh_f(aC1[r] + f16f((u16)(cc[r] >> 16)));
            float u0 = uu[0][r], u1 = uu[1][r];
            float hn0 = u0 * hold[0][r] + (1.0f - u0) * cd0;
            float hn1 = u1 * hold[1][r] + (1.0f - u1) * cd1;
            bool valid = t < (int)((lenp >> (8 * r)) & 255u);
            out[rowT[r] + tb + cO]      = valid ? hn0 : 0.0f;
            out[rowT[r] + tb + cO + 16] = valid ? hn1 : 0.0f;
            if (valid) {
                hold[0][r] = hn0; hold[1][r] = hn1;
                h_lds[qr * 4 + r][32 * w + cl]      = (_Float16)hn0;
                h_lds[qr * 4 + r][32 * w + 16 + cl] = (_Float16)hn1;
            }
        }
    }
}

extern "C" void kernel_launch(void* const* d_in, const int* in_sizes, int n_in,
                              void* d_out, int out_size, void* d_ws, size_t ws_size,
                              hipStream_t stream) {
    const float* x    = (const float*)d_in[0];
    const int*   slen = (const int*)  d_in[1];
    const float* gk   = (const float*)d_in[2];
    const float* gb   = (const float*)d_in[3];
    const float* ck   = (const float*)d_in[4];
    const float* cb   = (const float*)d_in[5];
    float* out = (float*)d_out;
    u32*   pgI = (u32*)d_out;   // [102400][256] u32 == 104.86 MB == out size
    u16*   pcI = (u16*)d_ws;    // [102400][256] u16 == 52.4 MB

    prep_wt<<<dim3(96), 512, 0, stream>>>(gk, ck);
    proj_mfma<<<dim3(1600), 512, 0, stream>>>(x, gb, cb, pgI, pcI);
    gru_rec6<<<dim3(32), 512, 0, stream>>>(slen, pgI, pcI, out);
}